// Round 14
// baseline (4552.863 us; speedup 1.0000x reference)
//
#include <hip/hip_runtime.h>
#include <hip/hip_bf16.h>
#include <cstdint>
#include <cstddef>

// Problem sizes (fixed)
#define B_SZ 8192
#define P_SZ 8
#define M_SZ 2048
#define C_SZ 1024

using bfrag = __attribute__((ext_vector_type(8))) short;          // 8 bf16 = 4 VGPR (MFMA A/B)
using facc  = __attribute__((ext_vector_type(4))) float;          // MFMA C/D frag
using f32x4 = __attribute__((ext_vector_type(4))) float;          // true vector f32x4 (NT store)
using u16x4 = __attribute__((ext_vector_type(4))) unsigned short;

typedef __attribute__((address_space(1))) const void g_void;
typedef __attribute__((address_space(3))) void l_void;

__device__ __forceinline__ unsigned short f2bf(float x) {
    union { __hip_bfloat16 h; unsigned short u; } cv;
    cv.h = __float2bfloat16(x);   // RNE
    return cv.u;
}
__device__ __forceinline__ float bf2f(unsigned short u) {
    union { unsigned int i; float f; } cv;
    cv.i = ((unsigned int)u) << 16;
    return cv.f;
}

// raw waits; barriers are the BUILTIN (machine-sched boundary). rule #18:
// sched_barrier(0) after inline-asm waitcnt so MFMA can't hoist past it.
#define WAIT_LGKM0() do { asm volatile("s_waitcnt lgkmcnt(0)" ::: "memory"); \
                          __builtin_amdgcn_sched_barrier(0); } while (0)
#define WAIT_VM(n)   do { asm volatile("s_waitcnt vmcnt(" #n ")" ::: "memory"); \
                          __builtin_amdgcn_sched_barrier(0); } while (0)
// legacy macros for the proven round-3 core (kept as-is)
#define S_BARRIER()     asm volatile("s_barrier" ::: "memory")
#define LGKM0_BARRIER() asm volatile("s_waitcnt lgkmcnt(0)\n\ts_barrier" ::: "memory")
#define WAIT_VM_RAW(n)  asm volatile("s_waitcnt vmcnt(" #n ")" ::: "memory")

// ---------------- pre-pass: fp32 -> bf16 conversions ----------------
__global__ void cvt_q_kernel(const float* __restrict__ in, unsigned short* __restrict__ q) {
    const size_t i = (size_t)blockIdx.x * blockDim.x + threadIdx.x;   // one float4 per thread
    const float4 v = ((const float4*)in)[i];
    u16x4 o = { f2bf(v.x), f2bf(v.y), f2bf(v.z), f2bf(v.w) };
    ((u16x4*)q)[i] = o;
}

// W fp32 [p][m][c] -> wb bf16 [p][m][c] and wt bf16 [p][c][m] (32x32 LDS tile transpose)
__global__ void cvt_w_kernel(const float* __restrict__ w,
                             unsigned short* __restrict__ wb,
                             unsigned short* __restrict__ wt) {
    __shared__ float t[32][33];
    const int bid = blockIdx.x;
    const int p  = bid >> 11;              // 2048 tiles per p (64 m-tiles * 32 c-tiles)
    const int m0 = ((bid >> 5) & 63) << 5;
    const int c0 = (bid & 31) << 5;
    const int tx = threadIdx.x & 7;        // c quad
    const int ty = threadIdx.x >> 3;       // m row 0..31
    const float4 v = *(const float4*)(w + ((size_t)p*M_SZ + m0 + ty)*C_SZ + c0 + tx*4);
    u16x4 o = { f2bf(v.x), f2bf(v.y), f2bf(v.z), f2bf(v.w) };
    *(u16x4*)(wb + ((size_t)p*M_SZ + m0 + ty)*C_SZ + c0 + tx*4) = o;
    t[ty][tx*4+0] = v.x; t[ty][tx*4+1] = v.y; t[ty][tx*4+2] = v.z; t[ty][tx*4+3] = v.w;
    __syncthreads();
    float4 u2;
    u2.x = t[tx*4+0][ty]; u2.y = t[tx*4+1][ty]; u2.z = t[tx*4+2][ty]; u2.w = t[tx*4+3][ty];
    u16x4 o2 = { f2bf(u2.x), f2bf(u2.y), f2bf(u2.z), f2bf(u2.w) };
    *(u16x4*)(wt + ((size_t)p*C_SZ + c0 + ty)*M_SZ + m0 + tx*4) = o2;
}

// ================= 4-phase 256x256 GEMM, parametric BK (round-14: BK=32, 2 blk/CU) ====
// K-loop: round-5 cadence generalized to BK. LDS = 2buf x (A + B) x 256 x BK x 2B:
// BK=32 -> 64KB -> 2 blocks/CU (4 waves/SIMD; cross-block overlap fills barrier
// stalls). Swizzle: chunk ^= r & (NCH-1); BK=32 rows (64B) split even/odd rows
// across bank halves -> balanced. Steady-state counted wait = 2 loads (vmcnt(2)).
// Epilogue: LDS-staged coalesced NT stores (round-13, proven).
template<int BK> constexpr int glds_bytes() { return 4 * 256 * BK * 2; }

template<int KLEN, int BK>
__device__ __forceinline__ void stage_half(const unsigned short* panelBase, char* ldsOp,
                                           int hh, int kt, int tid) {
    constexpr int RB  = BK * 2;            // row bytes
    constexpr int NCH = RB / 16;           // 16B chunks per row
    constexpr int HBY = 128 * RB;          // bytes per 128-row half
    constexpr int NLD = HBY / 8192;        // loads per thread (512 thr x 16B)
    #pragma unroll
    for (int i = 0; i < NLD; ++i) {
        const int o  = i*8192 + tid*16;    // byte offset within half
        const int rl = o / RB;             // local row
        const int r  = hh*128 + rl;        // tile row 0..255
        const int ps = (o % RB) >> 4;      // phys 16B chunk
        const int ls = ps ^ (r & (NCH-1)); // logical chunk (inverse swizzle on src)
        const unsigned short* src = panelBase + (size_t)r*KLEN + kt*BK + ls*8;
        char* dst = ldsOp + hh*HBY + i*8192 + ((tid >> 6) << 10);  // wave-uniform
        __builtin_amdgcn_global_load_lds((g_void*)src, (l_void*)dst, 16, 0, 0);
    }
}

template<int BK>
__device__ __forceinline__ void loadA(const char* ldsAbuf, int qm, int wm, int l15, int g,
                                      bfrag (&aF)[4][2]) {
    constexpr int RB = BK * 2, NCH = RB / 16, KS = BK / 32;
    #pragma unroll
    for (int mf = 0; mf < 4; ++mf) {
        const int r = qm*128 + wm*64 + mf*16 + l15;
        const char* rp = ldsAbuf + r*RB;
        #pragma unroll
        for (int ks = 0; ks < KS; ++ks)
            aF[mf][ks] = *(const bfrag*)(rp + (((ks*4 + g) ^ (r & (NCH-1))) << 4));
    }
}

template<int BK>
__device__ __forceinline__ void loadB(const char* ldsBbuf, int qn, int wn, int l15, int g,
                                      bfrag (&bF)[2][2]) {
    constexpr int RB = BK * 2, NCH = RB / 16, KS = BK / 32;
    #pragma unroll
    for (int nf = 0; nf < 2; ++nf) {
        const int r = qn*128 + wn*32 + nf*16 + l15;
        const char* rp = ldsBbuf + r*RB;
        #pragma unroll
        for (int ks = 0; ks < KS; ++ks)
            bF[nf][ks] = *(const bfrag*)(rp + (((ks*4 + g) ^ (r & (NCH-1))) << 4));
    }
}

template<int QM, int QN, int MODE, int DOSUM, int KS>
__device__ __forceinline__ void mfma_phase(const bfrag (&aF)[4][2], const bfrag (&bF)[2][2],
                                           facc (&acc)[8][4], float (&rs)[8]) {
    __builtin_amdgcn_s_setprio(1);
    #pragma unroll
    for (int ks = 0; ks < KS; ++ks)
        #pragma unroll
        for (int mf = 0; mf < 4; ++mf)
            #pragma unroll
            for (int nf = 0; nf < 2; ++nf)
                acc[QM*4 + mf][QN*2 + nf] = __builtin_amdgcn_mfma_f32_16x16x32_bf16(
                    aF[mf][ks], bF[nf][ks], acc[QM*4 + mf][QN*2 + nf], 0, 0, 0);
    if (MODE == 1 && DOSUM) {   // row-sum VALU co-issues with MFMA inside the pinned region
        #pragma unroll
        for (int mf = 0; mf < 4; ++mf)
            #pragma unroll
            for (int ks = 0; ks < KS; ++ks)
                #pragma unroll
                for (int e = 0; e < 8; ++e)
                    rs[QM*4 + mf] += bf2f((unsigned short)aF[mf][ks][e]);
    }
    __builtin_amdgcn_s_setprio(0);
}

// MODE 0: scores -> exp -> P bf16 [p][8192][2048] (NT stores)
// MODE 1: combine; in-loop register row-sum of A-frags = softmax denom; out f32 /denom (NT)
template<int KLEN, int NTN, int MODE, int BK>
__global__ __launch_bounds__(512, 4)
void gemmk(const unsigned short* __restrict__ A,
           const unsigned short* __restrict__ Bm,
           unsigned short* __restrict__ Pout,
           float* __restrict__ Oout,
           size_t APS, size_t BPS)
{
    extern __shared__ char lds[];
    constexpr int ABYTES = 256 * BK * 2;       // one operand tile
    constexpr int KS     = BK / 32;
    const int tid  = threadIdx.x;
    const int lane = tid & 63;
    const int wid  = tid >> 6;
    const int wm   = wid >> 2;     // 0..1
    const int wn   = wid & 3;      // 0..3
    const int g    = lane >> 4;
    const int l15  = lane & 15;

    const int p       = blockIdx.x & 7;      // p pinned per XCD
    const int logical = blockIdx.x >> 3;
    const int nt      = logical % NTN;
    const int mt      = logical / NTN;

    const unsigned short* Abase = A  + (size_t)p*APS + (size_t)mt*256*KLEN;
    const unsigned short* Bbase = Bm + (size_t)p*BPS + (size_t)nt*256*KLEN;

    facc acc[8][4];
    #pragma unroll
    for (int i = 0; i < 8; ++i)
        #pragma unroll
        for (int j = 0; j < 4; ++j) acc[i][j] = facc{0.f, 0.f, 0.f, 0.f};
    float rs[8] = {0.f,0.f,0.f,0.f,0.f,0.f,0.f,0.f};

    constexpr int NKT = KLEN / BK;

    // steady-state counted wait: leave the 2 most recent halves (2*NLD loads) in flight
#define WAIT_VM_STEADY() do { if constexpr (BK == 64) { WAIT_VM(4); } else { WAIT_VM(2); } } while (0)

    // ---- prologue: tile0 (4 halves) + A0,B1 of tile1 ----
    stage_half<KLEN,BK>(Bbase, lds + ABYTES,            0, 0, tid);
    stage_half<KLEN,BK>(Abase, lds + 0,                 0, 0, tid);
    stage_half<KLEN,BK>(Bbase, lds + ABYTES,            1, 0, tid);
    stage_half<KLEN,BK>(Abase, lds + 0,                 1, 0, tid);
    stage_half<KLEN,BK>(Abase, lds + 2*ABYTES,          0, (1 < NKT ? 1 : NKT-1), tid);
    stage_half<KLEN,BK>(Bbase, lds + 3*ABYTES,          1, (1 < NKT ? 1 : NKT-1), tid);
    WAIT_VM_STEADY();    // tile0's 4 halves landed; {A0(1),B1(1)} stay in flight
    __builtin_amdgcn_s_barrier();

    bfrag aF[4][2], bLow[2][2], bHigh[2][2];

    for (int t = 0; t < NKT; ++t) {
        const int cur = t & 1;
        char* ldsA  = lds + cur*2*ABYTES;
        char* ldsB  = ldsA + ABYTES;
        char* ldsAn = lds + (cur^1)*2*ABYTES;
        char* ldsBn = ldsAn + ABYTES;
        const int t1 = (t+1 < NKT) ? t+1 : NKT-1;
        const int t2 = (t+2 < NKT) ? t+2 : NKT-1;

        // ---- ph0: (qm0,qn0) ----
        loadA<BK>(ldsA, 0, wm, l15, g, aF);
        loadB<BK>(ldsB, 0, wn, l15, g, bLow);
        stage_half<KLEN,BK>(Bbase, ldsBn, 0, t1, tid);   // B0(t+1)
        __builtin_amdgcn_s_barrier();
        WAIT_LGKM0();
        mfma_phase<0,0,MODE,1,KS>(aF, bLow, acc, rs);
        __builtin_amdgcn_s_barrier();

        // ---- ph1: (qm0,qn1) ----
        loadB<BK>(ldsB, 1, wn, l15, g, bHigh);
        stage_half<KLEN,BK>(Abase, ldsAn, 1, t1, tid);   // A1(t+1)
        __builtin_amdgcn_s_barrier();
        WAIT_LGKM0();
        mfma_phase<0,1,MODE,0,KS>(aF, bHigh, acc, rs);
        __builtin_amdgcn_s_barrier();

        // ---- ph2: (qm1,qn1) ----
        loadA<BK>(ldsA, 1, wm, l15, g, aF);
        stage_half<KLEN,BK>(Abase, ldsA, 0, t2, tid);    // A0(t+2) -> cur (A-low consumed)
        __builtin_amdgcn_s_barrier();
        WAIT_LGKM0();
        mfma_phase<1,1,MODE,1,KS>(aF, bHigh, acc, rs);
        __builtin_amdgcn_s_barrier();

        // ---- ph3: (qm1,qn0) ----
        stage_half<KLEN,BK>(Bbase, ldsB, 1, t2, tid);    // B1(t+2) -> cur (B-high consumed)
        __builtin_amdgcn_s_barrier();
        mfma_phase<1,0,MODE,0,KS>(aF, bLow, acc, rs);
        WAIT_VM_STEADY();  // admit tile t+1; {A0(t+2),B1(t+2)} stay in flight
        __builtin_amdgcn_s_barrier();
    }
#undef WAIT_VM_STEADY

    // ---- epilogue: LDS-staged, fully coalesced NON-TEMPORAL global stores ----
    const int row0g = mt*256;
    const int col0g = nt*256;
    __syncthreads();   // drain in-flight global_load_lds (they target lds) + barrier

    if (MODE == 0) {
        unsigned short* Pp = Pout + (size_t)p * ((size_t)B_SZ * M_SZ);
        unsigned short* plds = (unsigned short*)lds;          // [128][256] bf16 = 64KB
        #pragma unroll
        for (int c2 = 0; c2 < 2; ++c2) {                      // qm = c2
            #pragma unroll
            for (int mf = 0; mf < 4; ++mf)
                #pragma unroll
                for (int j = 0; j < 4; ++j) {
                    const int r = wm*64 + mf*16 + g*4 + j;    // 0..127
                    #pragma unroll
                    for (int qn = 0; qn < 2; ++qn)
                        #pragma unroll
                        for (int nf = 0; nf < 2; ++nf)
                            plds[r*256 + qn*128 + wn*32 + nf*16 + l15] =
                                f2bf(__expf(acc[c2*4+mf][qn*2+nf][j]));
                }
            WAIT_LGKM0();
            __builtin_amdgcn_s_barrier();
            #pragma unroll
            for (int i = 0; i < 8; ++i) {                     // 64KB / 512thr / 16B = 8
                const int o  = i*8192 + tid*16;
                const int r  = o >> 9;                        // 512B LDS rows
                const int cb = o & 511;
                const bfrag v = *(const bfrag*)((char*)plds + o);
                __builtin_nontemporal_store(v,
                    (bfrag*)((char*)(Pp + (size_t)(row0g + c2*128 + r)*M_SZ + col0g) + cb));
            }
            WAIT_LGKM0();                                     // reads retired before rewrite
            __builtin_amdgcn_s_barrier();
        }
    } else {
        float* flds = (float*)lds;                            // [64][256] f32 = 64KB
        #pragma unroll
        for (int c2 = 0; c2 < 4; ++c2) {                      // rows c2*64..+63
            const int qm = c2 >> 1;
            if (wm == (c2 & 1)) {                             // wave-uniform branch
                #pragma unroll
                for (int mf = 0; mf < 4; ++mf) {
                    float d = rs[qm*4 + mf];
                    d += __shfl_xor(d, 16);
                    d += __shfl_xor(d, 32);                   // full row sum (4 g-groups)
                    #pragma unroll
                    for (int j = 0; j < 4; ++j) {
                        const float inv = 1.0f / __shfl(d, g*4 + j);
                        const int r = mf*16 + g*4 + j;        // 0..63
                        #pragma unroll
                        for (int qn = 0; qn < 2; ++qn)
                            #pragma unroll
                            for (int nf = 0; nf < 2; ++nf)
                                flds[r*256 + qn*128 + wn*32 + nf*16 + l15] =
                                    acc[qm*4+mf][qn*2+nf][j] * inv;
                    }
                }
            }
            WAIT_LGKM0();
            __builtin_amdgcn_s_barrier();
            #pragma unroll
            for (int i = 0; i < 8; ++i) {                     // 64KB / 512thr / 16B = 8
                const int o  = i*8192 + tid*16;
                const int r  = o >> 10;                       // 1024B LDS rows (256 f32)
                const int cb = o & 1023;
                const f32x4 v = *(const f32x4*)((char*)flds + o);
                __builtin_nontemporal_store(v,
                    (f32x4*)((char*)(Oout + ((size_t)(row0g + c2*64 + r)*P_SZ + p)*C_SZ + col0g) + cb));
            }
            WAIT_LGKM0();
            __builtin_amdgcn_s_barrier();
        }
    }
}

// ================= round-3 decoupled 128^2 core (fallback tier, proven ~910TF) ==========
template<int KLEN, int NTN, int CPX, int MODE>
__global__ __launch_bounds__(256, 2)
void gemm_tile(const unsigned short* __restrict__ A,
               const unsigned short* __restrict__ Bm,
               unsigned short* __restrict__ Pout,
               float* __restrict__ Oout,
               int p)
{
    __shared__ alignas(16) char lds[32768];
    const int tid  = threadIdx.x;
    const int lane = tid & 63;
    const int wid  = tid >> 6;
    const int wr   = wid >> 1;
    const int wc   = wid & 1;
    const int g    = lane >> 4;
    const int l15  = lane & 15;

    const int logical = (blockIdx.x & 7) * CPX + (blockIdx.x >> 3);
    const int mt = logical / NTN;
    const int nt = logical % NTN;

    const unsigned short* Abase = A  + (size_t)mt * 128 * KLEN;
    const unsigned short* Bbase = Bm + (size_t)nt * 128 * KLEN;

    facc acc[4][4];
    #pragma unroll
    for (int i = 0; i < 4; ++i)
        #pragma unroll
        for (int j = 0; j < 4; ++j) acc[i][j] = facc{0.f, 0.f, 0.f, 0.f};
    float rs[4] = {0.f, 0.f, 0.f, 0.f};

    constexpr int NKT = KLEN / 32;

    auto stage = [&](int kt) {
        char* buf = lds + (kt & 1) * 16384;
        const unsigned short* As = Abase + kt * 32;
        const unsigned short* Bs = Bbase + kt * 32;
        #pragma unroll
        for (int i = 0; i < 2; ++i) {
            const int o  = i * 4096 + tid * 16;
            const int r  = o >> 6;
            const int s  = (o >> 4) & 3;
            const int cs = s ^ ((r >> 1) & 3);
            __builtin_amdgcn_global_load_lds((g_void*)(As + (size_t)r * KLEN + cs * 8),
                                             (l_void*)(buf + i * 4096 + ((tid >> 6) << 10)),
                                             16, 0, 0);
        }
        #pragma unroll
        for (int i = 0; i < 2; ++i) {
            const int o  = i * 4096 + tid * 16;
            const int r  = o >> 6;
            const int s  = (o >> 4) & 3;
            const int cs = s ^ ((r >> 1) & 3);
            __builtin_amdgcn_global_load_lds((g_void*)(Bs + (size_t)r * KLEN + cs * 8),
                                             (l_void*)(buf + 8192 + i * 4096 + ((tid >> 6) << 10)),
                                             16, 0, 0);
        }
    };

    stage(0);
    stage(1);

    const int cb = ((((l15 >> 1) & 3) ^ g) << 4);

    for (int kt = 0; kt < NKT; ++kt) {
        if (kt + 1 < NKT) { WAIT_VM_RAW(4); } else { WAIT_VM_RAW(0); }
        S_BARRIER();
        const char* Ab = lds + (kt & 1) * 16384;
        const char* Bb = Ab + 8192;
        bfrag af[4], bb[4];
        #pragma unroll
        for (int mf = 0; mf < 4; ++mf)
            af[mf] = *(const bfrag*)(Ab + (wr * 64 + mf * 16 + l15) * 64 + cb);
        #pragma unroll
        for (int nf = 0; nf < 4; ++nf)
            bb[nf] = *(const bfrag*)(Bb + (wc * 64 + nf * 16 + l15) * 64 + cb);
        LGKM0_BARRIER();
        if (kt + 2 < NKT) stage(kt + 2);
        if (MODE == 1) {
            #pragma unroll
            for (int mf = 0; mf < 4; ++mf)
                #pragma unroll
                for (int e = 0; e < 8; ++e)
                    rs[mf] += bf2f((unsigned short)af[mf][e]);
        }
        #pragma unroll
        for (int mf = 0; mf < 4; ++mf)
            #pragma unroll
            for (int nf = 0; nf < 4; ++nf)
                acc[mf][nf] = __builtin_amdgcn_mfma_f32_16x16x32_bf16(af[mf], bb[nf], acc[mf][nf], 0, 0, 0);
    }

    if (MODE == 0) {
        const int prow0 = mt * 128 + wr * 64;
        const int pcol0 = nt * 128 + wc * 64;
        #pragma unroll
        for (int mf = 0; mf < 4; ++mf)
            #pragma unroll
            for (int j = 0; j < 4; ++j) {
                const size_t rbase = (size_t)(prow0 + mf * 16 + g * 4 + j) * M_SZ + pcol0 + l15;
                #pragma unroll
                for (int nf = 0; nf < 4; ++nf)
                    Pout[rbase + nf * 16] = f2bf(__expf(acc[mf][nf][j]));
            }
    } else {
        const int orow0 = mt * 128 + wr * 64;
        const int ocol0 = nt * 128 + wc * 64;
        #pragma unroll
        for (int mf = 0; mf < 4; ++mf) {
            float d = rs[mf];
            d += __shfl_xor(d, 16);
            d += __shfl_xor(d, 32);
            #pragma unroll
            for (int j = 0; j < 4; ++j) {
                const float inv = 1.0f / __shfl(d, g * 4 + j);
                const size_t rbase = ((size_t)(orow0 + mf * 16 + g * 4 + j) * P_SZ + p) * C_SZ
                                   + ocol0 + l15;
                #pragma unroll
                for (int nf = 0; nf < 4; ++nf)
                    Oout[rbase + nf * 16] = acc[mf][nf][j] * inv;
            }
        }
    }
}

// ---------------- emergency fallback (no workspace): fp32, slow but correct ----------------
__global__ void emu_fallback(const float* __restrict__ inF, const float* __restrict__ wF,
                             float* __restrict__ out)
{
    __shared__ float sc[M_SZ];
    __shared__ float qs[C_SZ];
    __shared__ float wsum[4];
    const int b = blockIdx.x;
    const int tid = threadIdx.x;           // 256
    for (int c = tid; c < C_SZ; c += 256) qs[c] = inF[(size_t)b*C_SZ + c];
    __syncthreads();
    for (int p = 0; p < P_SZ; ++p) {
        const float* wp = wF + (size_t)p*M_SZ*C_SZ;
        for (int m = tid; m < M_SZ; m += 256) {
            float d = 0.f;
            const float* wr = wp + (size_t)m*C_SZ;
            for (int c = 0; c < C_SZ; ++c) d += qs[c]*wr[c];
            sc[m] = __expf(d);
        }
        __syncthreads();
        float part = 0.f;
        for (int m = tid; m < M_SZ; m += 256) part += sc[m];
        #pragma unroll
        for (int sft = 1; sft < 64; sft <<= 1) part += __shfl_xor(part, sft);
        if ((tid & 63) == 0) wsum[tid >> 6] = part;
        __syncthreads();
        const float rin = 1.0f / (wsum[0] + wsum[1] + wsum[2] + wsum[3]);
        float o0=0,o1=0,o2=0,o3=0;
        for (int m = 0; m < M_SZ; ++m) {
            const float pm = sc[m];
            const float4 w4 = *(const float4*)(wp + (size_t)m*C_SZ + tid*4);
            o0 += pm*w4.x; o1 += pm*w4.y; o2 += pm*w4.z; o3 += pm*w4.w;
        }
        float* op = out + ((size_t)b*P_SZ + p)*C_SZ + tid*4;
        op[0]=o0*rin; op[1]=o1*rin; op[2]=o2*rin; op[3]=o3*rin;
        __syncthreads();
    }
}

// ---------------- launcher ----------------
extern "C" void kernel_launch(void* const* d_in, const int* in_sizes, int n_in,
                              void* d_out, int out_size, void* d_ws, size_t ws_size,
                              hipStream_t stream)
{
    (void)in_sizes; (void)n_in; (void)out_size;
    const float* inF = (const float*)d_in[0];
    const float* wF  = (const float*)d_in[1];
    float* out = (float*)d_out;

    const size_t wbE  = (size_t)P_SZ * M_SZ * C_SZ;    // 16M
    const size_t qE   = (size_t)B_SZ * C_SZ;           // 8M
    const size_t pME  = (size_t)B_SZ * M_SZ;           // 16M (one p's P panel)
    const size_t pAll = pME * P_SZ;                    // 128M (all-p P)
    const size_t needBig   = (wbE*2 + qE + pAll) * sizeof(unsigned short);  // ~352 MB
    const size_t needMid   = (wbE*2 + qE + pME)  * sizeof(unsigned short);  // ~117 MB

    if (ws_size >= needBig) {
        unsigned short* wb = (unsigned short*)d_ws;
        unsigned short* wt = wb + wbE;
        unsigned short* qb = wt + wbE;
        unsigned short* Pb = qb + qE;
        cvt_q_kernel<<<(unsigned)(qE/4/256), 256, 0, stream>>>(inF, qb);
        cvt_w_kernel<<<P_SZ*64*32, 256, 0, stream>>>(wF, wb, wt);
        constexpr int BKR = 32;
        constexpr int LDSB = glds_bytes<BKR>();        // 64 KB -> 2 blocks/CU
        // GEMM1 all-p: S = Q * W_p^T -> exp -> P   (per p: M=8192, N=2048, K=1024)
        hipError_t e0 = hipFuncSetAttribute(reinterpret_cast<const void*>(&gemmk<C_SZ, 8, 0, BKR>),
                            hipFuncAttributeMaxDynamicSharedMemorySize, LDSB);
        (void)e0;
        gemmk<C_SZ, 8, 0, BKR><<<2048, 512, LDSB, stream>>>(
            qb, wb, Pb, nullptr, (size_t)0, (size_t)M_SZ * C_SZ);
        // GEMM2 all-p: O = P * W_p / denom        (per p: M=8192, N=1024, K=2048)
        hipError_t e1 = hipFuncSetAttribute(reinterpret_cast<const void*>(&gemmk<M_SZ, 4, 1, BKR>),
                            hipFuncAttributeMaxDynamicSharedMemorySize, LDSB);
        (void)e1;
        gemmk<M_SZ, 4, 1, BKR><<<1024, 512, LDSB, stream>>>(
            Pb, wt, nullptr, out, (size_t)B_SZ * M_SZ, (size_t)C_SZ * M_SZ);
    } else if (ws_size >= needMid) {
        unsigned short* wb = (unsigned short*)d_ws;
        unsigned short* wt = wb + wbE;
        unsigned short* qb = wt + wbE;
        unsigned short* Pb = qb + qE;
        cvt_q_kernel<<<(unsigned)(qE/4/256), 256, 0, stream>>>(inF, qb);
        cvt_w_kernel<<<P_SZ*64*32, 256, 0, stream>>>(wF, wb, wt);
        for (int p = 0; p < P_SZ; ++p) {
            gemm_tile<C_SZ, 16, 128, 0><<<1024, 256, 0, stream>>>(
                qb, wb + (size_t)p*M_SZ*C_SZ, Pb, nullptr, p);
            gemm_tile<M_SZ, 8, 64, 1><<<512, 256, 0, stream>>>(
                Pb, wt + (size_t)p*C_SZ*M_SZ, nullptr, out, p);
        }
    } else {
        emu_fallback<<<B_SZ, 256, 0, stream>>>(inF, wF, out);
    }
}

// Round 15
// 631.771 us; speedup vs baseline: 7.2065x; 7.2065x over previous
//
#include <hip/hip_runtime.h>
#include <hip/hip_bf16.h>
#include <cstdint>
#include <cstddef>

// Problem sizes (fixed)
#define B_SZ 8192
#define P_SZ 8
#define M_SZ 2048
#define C_SZ 1024

using bfrag = __attribute__((ext_vector_type(8))) short;          // 8 bf16 = 4 VGPR (MFMA A/B)
using facc  = __attribute__((ext_vector_type(4))) float;          // MFMA C/D frag
using f32x4 = __attribute__((ext_vector_type(4))) float;          // true vector f32x4 (NT store)
using u16x4 = __attribute__((ext_vector_type(4))) unsigned short;

typedef __attribute__((address_space(1))) const void g_void;
typedef __attribute__((address_space(3))) void l_void;

__device__ __forceinline__ unsigned short f2bf(float x) {
    union { __hip_bfloat16 h; unsigned short u; } cv;
    cv.h = __float2bfloat16(x);   // RNE
    return cv.u;
}
__device__ __forceinline__ float bf2f(unsigned short u) {
    union { unsigned int i; float f; } cv;
    cv.i = ((unsigned int)u) << 16;
    return cv.f;
}

// raw waits; barriers are the BUILTIN (machine-sched boundary). rule #18:
// sched_barrier(0) after inline-asm waitcnt so MFMA can't hoist past it.
#define WAIT_LGKM0() do { asm volatile("s_waitcnt lgkmcnt(0)" ::: "memory"); \
                          __builtin_amdgcn_sched_barrier(0); } while (0)
#define WAIT_VM(n)   do { asm volatile("s_waitcnt vmcnt(" #n ")" ::: "memory"); \
                          __builtin_amdgcn_sched_barrier(0); } while (0)
// legacy macros for the proven round-3 core (kept as-is)
#define S_BARRIER()     asm volatile("s_barrier" ::: "memory")
#define LGKM0_BARRIER() asm volatile("s_waitcnt lgkmcnt(0)\n\ts_barrier" ::: "memory")
#define WAIT_VM_RAW(n)  asm volatile("s_waitcnt vmcnt(" #n ")" ::: "memory")

// ---------------- pre-pass: fp32 -> bf16 conversions ----------------
__global__ void cvt_q_kernel(const float* __restrict__ in, unsigned short* __restrict__ q) {
    const size_t i = (size_t)blockIdx.x * blockDim.x + threadIdx.x;   // one float4 per thread
    const float4 v = ((const float4*)in)[i];
    u16x4 o = { f2bf(v.x), f2bf(v.y), f2bf(v.z), f2bf(v.w) };
    ((u16x4*)q)[i] = o;
}

// W fp32 [p][m][c] -> wb bf16 [p][m][c] and wt bf16 [p][c][m] (32x32 LDS tile transpose)
__global__ void cvt_w_kernel(const float* __restrict__ w,
                             unsigned short* __restrict__ wb,
                             unsigned short* __restrict__ wt) {
    __shared__ float t[32][33];
    const int bid = blockIdx.x;
    const int p  = bid >> 11;              // 2048 tiles per p (64 m-tiles * 32 c-tiles)
    const int m0 = ((bid >> 5) & 63) << 5;
    const int c0 = (bid & 31) << 5;
    const int tx = threadIdx.x & 7;        // c quad
    const int ty = threadIdx.x >> 3;       // m row 0..31
    const float4 v = *(const float4*)(w + ((size_t)p*M_SZ + m0 + ty)*C_SZ + c0 + tx*4);
    u16x4 o = { f2bf(v.x), f2bf(v.y), f2bf(v.z), f2bf(v.w) };
    *(u16x4*)(wb + ((size_t)p*M_SZ + m0 + ty)*C_SZ + c0 + tx*4) = o;
    t[ty][tx*4+0] = v.x; t[ty][tx*4+1] = v.y; t[ty][tx*4+2] = v.z; t[ty][tx*4+3] = v.w;
    __syncthreads();
    float4 u2;
    u2.x = t[tx*4+0][ty]; u2.y = t[tx*4+1][ty]; u2.z = t[tx*4+2][ty]; u2.w = t[tx*4+3][ty];
    u16x4 o2 = { f2bf(u2.x), f2bf(u2.y), f2bf(u2.z), f2bf(u2.w) };
    *(u16x4*)(wt + ((size_t)p*C_SZ + c0 + ty)*M_SZ + m0 + tx*4) = o2;
}

// ================= 8-phase 256x256 GEMM (round-5 K-loop + LDS-staged NT epilogue) =====
// Best measured configuration (round 13: 632.98 us). 1 block/CU is structural:
// acc[8][4] f32 + temps needs >128 VGPR, so forcing 2 blocks/CU spills (round 14).
constexpr int GLDS = 131072;

template<int KLEN>
__device__ __forceinline__ void stage_half8(const unsigned short* panelBase, char* ldsOp,
                                            int hh, int kt, int tid) {
    #pragma unroll
    for (int i = 0; i < 2; ++i) {
        const int o  = i*8192 + tid*16;        // byte offset within 16KB half
        const int rl = o >> 7;                 // local row (128B rows)
        const int r  = hh*128 + rl;            // tile row 0..255
        const int ps = (o >> 4) & 7;           // phys 16B chunk
        const int ls = ps ^ (r & 7);           // logical chunk (inverse swizzle on src)
        const unsigned short* src = panelBase + (size_t)r*KLEN + kt*64 + ls*8;
        char* dst = ldsOp + hh*16384 + i*8192 + ((tid >> 6) << 10);  // wave-uniform
        __builtin_amdgcn_global_load_lds((g_void*)src, (l_void*)dst, 16, 0, 0);
    }
}

__device__ __forceinline__ void loadA8(const char* ldsAbuf, int qm, int wm, int l15, int g,
                                       bfrag (&aF)[4][2]) {
    #pragma unroll
    for (int mf = 0; mf < 4; ++mf) {
        const int r = qm*128 + wm*64 + mf*16 + l15;
        const char* rp = ldsAbuf + r*128;
        #pragma unroll
        for (int ks = 0; ks < 2; ++ks)
            aF[mf][ks] = *(const bfrag*)(rp + (((ks*4 + g) ^ (r & 7)) << 4));
    }
}

__device__ __forceinline__ void loadB8(const char* ldsBbuf, int qn, int wn, int l15, int g,
                                       bfrag (&bF)[2][2]) {
    #pragma unroll
    for (int nf = 0; nf < 2; ++nf) {
        const int r = qn*128 + wn*32 + nf*16 + l15;
        const char* rp = ldsBbuf + r*128;
        #pragma unroll
        for (int ks = 0; ks < 2; ++ks)
            bF[nf][ks] = *(const bfrag*)(rp + (((ks*4 + g) ^ (r & 7)) << 4));
    }
}

template<int QM, int QN, int MODE, int DOSUM>
__device__ __forceinline__ void mfma_phase(const bfrag (&aF)[4][2], const bfrag (&bF)[2][2],
                                           facc (&acc)[8][4], float (&rs)[8]) {
    __builtin_amdgcn_s_setprio(1);
    #pragma unroll
    for (int ks = 0; ks < 2; ++ks)
        #pragma unroll
        for (int mf = 0; mf < 4; ++mf)
            #pragma unroll
            for (int nf = 0; nf < 2; ++nf)
                acc[QM*4 + mf][QN*2 + nf] = __builtin_amdgcn_mfma_f32_16x16x32_bf16(
                    aF[mf][ks], bF[nf][ks], acc[QM*4 + mf][QN*2 + nf], 0, 0, 0);
    if (MODE == 1 && DOSUM) {   // row-sum VALU co-issues with MFMA inside the pinned region
        #pragma unroll
        for (int mf = 0; mf < 4; ++mf)
            #pragma unroll
            for (int ks = 0; ks < 2; ++ks)
                #pragma unroll
                for (int e = 0; e < 8; ++e)
                    rs[QM*4 + mf] += bf2f((unsigned short)aF[mf][ks][e]);
    }
    __builtin_amdgcn_s_setprio(0);
}

// MODE 0: scores -> exp -> P bf16 [p][8192][2048] (NT stores)
// MODE 1: combine; in-loop register row-sum of A-frags = softmax denom; out f32 /denom (NT)
template<int KLEN, int NTN, int MODE>
__global__ __launch_bounds__(512, 2)
void gemm8(const unsigned short* __restrict__ A,
           const unsigned short* __restrict__ Bm,
           unsigned short* __restrict__ Pout,
           float* __restrict__ Oout,
           size_t APS, size_t BPS)
{
    extern __shared__ char lds[];
    const int tid  = threadIdx.x;
    const int lane = tid & 63;
    const int wid  = tid >> 6;
    const int wm   = wid >> 2;     // 0..1
    const int wn   = wid & 3;      // 0..3
    const int g    = lane >> 4;
    const int l15  = lane & 15;

    const int p       = blockIdx.x & 7;      // p pinned per XCD
    const int logical = blockIdx.x >> 3;
    const int nt      = logical % NTN;
    const int mt      = logical / NTN;

    const unsigned short* Abase = A  + (size_t)p*APS + (size_t)mt*256*KLEN;
    const unsigned short* Bbase = Bm + (size_t)p*BPS + (size_t)nt*256*KLEN;

    facc acc[8][4];
    #pragma unroll
    for (int i = 0; i < 8; ++i)
        #pragma unroll
        for (int j = 0; j < 4; ++j) acc[i][j] = facc{0.f, 0.f, 0.f, 0.f};
    float rs[8] = {0.f,0.f,0.f,0.f,0.f,0.f,0.f,0.f};

    constexpr int NKT = KLEN / 64;

    // ---- prologue: tile0 (4 halves) + A0,B1 of tile1 ----
    stage_half8<KLEN>(Bbase, lds + 32768,         0, 0, tid);
    stage_half8<KLEN>(Abase, lds + 0,             0, 0, tid);
    stage_half8<KLEN>(Bbase, lds + 32768,         1, 0, tid);
    stage_half8<KLEN>(Abase, lds + 0,             1, 0, tid);
    stage_half8<KLEN>(Abase, lds + 65536,         0, (1 < NKT ? 1 : NKT-1), tid);
    stage_half8<KLEN>(Bbase, lds + 65536 + 32768, 1, (1 < NKT ? 1 : NKT-1), tid);
    WAIT_VM(4);          // tile0's 4 halves landed; {A0(1),B1(1)} stay in flight
    __builtin_amdgcn_s_barrier();

    bfrag aF[4][2], bLow[2][2], bHigh[2][2];

    for (int t = 0; t < NKT; ++t) {
        const int cur = t & 1;
        char* ldsA  = lds + cur*65536;
        char* ldsB  = ldsA + 32768;
        char* ldsAn = lds + (cur^1)*65536;
        char* ldsBn = ldsAn + 32768;
        const int t1 = (t+1 < NKT) ? t+1 : NKT-1;
        const int t2 = (t+2 < NKT) ? t+2 : NKT-1;

        // ---- ph0: (qm0,qn0) ----
        loadA8(ldsA, 0, wm, l15, g, aF);
        loadB8(ldsB, 0, wn, l15, g, bLow);
        stage_half8<KLEN>(Bbase, ldsBn, 0, t1, tid);   // B0(t+1)
        __builtin_amdgcn_s_barrier();
        WAIT_LGKM0();
        mfma_phase<0,0,MODE,1>(aF, bLow, acc, rs);
        __builtin_amdgcn_s_barrier();

        // ---- ph1: (qm0,qn1) ----
        loadB8(ldsB, 1, wn, l15, g, bHigh);
        stage_half8<KLEN>(Abase, ldsAn, 1, t1, tid);   // A1(t+1)
        __builtin_amdgcn_s_barrier();
        WAIT_LGKM0();
        mfma_phase<0,1,MODE,0>(aF, bHigh, acc, rs);
        __builtin_amdgcn_s_barrier();

        // ---- ph2: (qm1,qn1) ----
        loadA8(ldsA, 1, wm, l15, g, aF);
        stage_half8<KLEN>(Abase, ldsA, 0, t2, tid);    // A0(t+2) -> cur (A-low consumed)
        __builtin_amdgcn_s_barrier();
        WAIT_LGKM0();
        mfma_phase<1,1,MODE,1>(aF, bHigh, acc, rs);
        __builtin_amdgcn_s_barrier();

        // ---- ph3: (qm1,qn0) ----
        stage_half8<KLEN>(Bbase, ldsB, 1, t2, tid);    // B1(t+2) -> cur (B-high consumed)
        __builtin_amdgcn_s_barrier();
        mfma_phase<1,0,MODE,0>(aF, bLow, acc, rs);
        WAIT_VM(4);        // admit tile t+1; {A0(t+2),B1(t+2)} stay in flight
        __builtin_amdgcn_s_barrier();
    }

    // ---- epilogue: LDS-staged, fully coalesced NON-TEMPORAL global stores ----
    const int row0g = mt*256;
    const int col0g = nt*256;
    __syncthreads();   // drain in-flight global_load_lds (they target lds) + barrier

    if (MODE == 0) {
        unsigned short* Pp = Pout + (size_t)p * ((size_t)B_SZ * M_SZ);
        unsigned short* plds = (unsigned short*)lds;          // [128][256] bf16 = 64KB
        #pragma unroll
        for (int c2 = 0; c2 < 2; ++c2) {                      // qm = c2
            #pragma unroll
            for (int mf = 0; mf < 4; ++mf)
                #pragma unroll
                for (int j = 0; j < 4; ++j) {
                    const int r = wm*64 + mf*16 + g*4 + j;    // 0..127
                    #pragma unroll
                    for (int qn = 0; qn < 2; ++qn)
                        #pragma unroll
                        for (int nf = 0; nf < 2; ++nf)
                            plds[r*256 + qn*128 + wn*32 + nf*16 + l15] =
                                f2bf(__expf(acc[c2*4+mf][qn*2+nf][j]));
                }
            WAIT_LGKM0();
            __builtin_amdgcn_s_barrier();
            #pragma unroll
            for (int i = 0; i < 8; ++i) {                     // 64KB / 512thr / 16B = 8
                const int o  = i*8192 + tid*16;
                const int r  = o >> 9;                        // 512B LDS rows
                const int cb = o & 511;
                const bfrag v = *(const bfrag*)((char*)plds + o);
                __builtin_nontemporal_store(v,
                    (bfrag*)((char*)(Pp + (size_t)(row0g + c2*128 + r)*M_SZ + col0g) + cb));
            }
            WAIT_LGKM0();                                     // reads retired before rewrite
            __builtin_amdgcn_s_barrier();
        }
    } else {
        float* flds = (float*)lds;                            // [64][256] f32 = 64KB
        #pragma unroll
        for (int c2 = 0; c2 < 4; ++c2) {                      // rows c2*64..+63
            const int qm = c2 >> 1;
            if (wm == (c2 & 1)) {                             // wave-uniform branch
                #pragma unroll
                for (int mf = 0; mf < 4; ++mf) {
                    float d = rs[qm*4 + mf];
                    d += __shfl_xor(d, 16);
                    d += __shfl_xor(d, 32);                   // full row sum (4 g-groups)
                    #pragma unroll
                    for (int j = 0; j < 4; ++j) {
                        const float inv = 1.0f / __shfl(d, g*4 + j);
                        const int r = mf*16 + g*4 + j;        // 0..63
                        #pragma unroll
                        for (int qn = 0; qn < 2; ++qn)
                            #pragma unroll
                            for (int nf = 0; nf < 2; ++nf)
                                flds[r*256 + qn*128 + wn*32 + nf*16 + l15] =
                                    acc[qm*4+mf][qn*2+nf][j] * inv;
                    }
                }
            }
            WAIT_LGKM0();
            __builtin_amdgcn_s_barrier();
            #pragma unroll
            for (int i = 0; i < 8; ++i) {                     // 64KB / 512thr / 16B = 8
                const int o  = i*8192 + tid*16;
                const int r  = o >> 10;                       // 1024B LDS rows (256 f32)
                const int cb = o & 1023;
                const f32x4 v = *(const f32x4*)((char*)flds + o);
                __builtin_nontemporal_store(v,
                    (f32x4*)((char*)(Oout + ((size_t)(row0g + c2*64 + r)*P_SZ + p)*C_SZ + col0g) + cb));
            }
            WAIT_LGKM0();
            __builtin_amdgcn_s_barrier();
        }
    }
}

// ================= round-3 decoupled 128^2 core (fallback tier, proven ~910TF) ==========
template<int KLEN, int NTN, int CPX, int MODE>
__global__ __launch_bounds__(256, 2)
void gemm_tile(const unsigned short* __restrict__ A,
               const unsigned short* __restrict__ Bm,
               unsigned short* __restrict__ Pout,
               float* __restrict__ Oout,
               int p)
{
    __shared__ alignas(16) char lds[32768];
    const int tid  = threadIdx.x;
    const int lane = tid & 63;
    const int wid  = tid >> 6;
    const int wr   = wid >> 1;
    const int wc   = wid & 1;
    const int g    = lane >> 4;
    const int l15  = lane & 15;

    const int logical = (blockIdx.x & 7) * CPX + (blockIdx.x >> 3);
    const int mt = logical / NTN;
    const int nt = logical % NTN;

    const unsigned short* Abase = A  + (size_t)mt * 128 * KLEN;
    const unsigned short* Bbase = Bm + (size_t)nt * 128 * KLEN;

    facc acc[4][4];
    #pragma unroll
    for (int i = 0; i < 4; ++i)
        #pragma unroll
        for (int j = 0; j < 4; ++j) acc[i][j] = facc{0.f, 0.f, 0.f, 0.f};
    float rs[4] = {0.f, 0.f, 0.f, 0.f};

    constexpr int NKT = KLEN / 32;

    auto stage = [&](int kt) {
        char* buf = lds + (kt & 1) * 16384;
        const unsigned short* As = Abase + kt * 32;
        const unsigned short* Bs = Bbase + kt * 32;
        #pragma unroll
        for (int i = 0; i < 2; ++i) {
            const int o  = i * 4096 + tid * 16;
            const int r  = o >> 6;
            const int s  = (o >> 4) & 3;
            const int cs = s ^ ((r >> 1) & 3);
            __builtin_amdgcn_global_load_lds((g_void*)(As + (size_t)r * KLEN + cs * 8),
                                             (l_void*)(buf + i * 4096 + ((tid >> 6) << 10)),
                                             16, 0, 0);
        }
        #pragma unroll
        for (int i = 0; i < 2; ++i) {
            const int o  = i * 4096 + tid * 16;
            const int r  = o >> 6;
            const int s  = (o >> 4) & 3;
            const int cs = s ^ ((r >> 1) & 3);
            __builtin_amdgcn_global_load_lds((g_void*)(Bs + (size_t)r * KLEN + cs * 8),
                                             (l_void*)(buf + 8192 + i * 4096 + ((tid >> 6) << 10)),
                                             16, 0, 0);
        }
    };

    stage(0);
    stage(1);

    const int cb = ((((l15 >> 1) & 3) ^ g) << 4);

    for (int kt = 0; kt < NKT; ++kt) {
        if (kt + 1 < NKT) { WAIT_VM_RAW(4); } else { WAIT_VM_RAW(0); }
        S_BARRIER();
        const char* Ab = lds + (kt & 1) * 16384;
        const char* Bb = Ab + 8192;
        bfrag af[4], bb[4];
        #pragma unroll
        for (int mf = 0; mf < 4; ++mf)
            af[mf] = *(const bfrag*)(Ab + (wr * 64 + mf * 16 + l15) * 64 + cb);
        #pragma unroll
        for (int nf = 0; nf < 4; ++nf)
            bb[nf] = *(const bfrag*)(Bb + (wc * 64 + nf * 16 + l15) * 64 + cb);
        LGKM0_BARRIER();
        if (kt + 2 < NKT) stage(kt + 2);
        if (MODE == 1) {
            #pragma unroll
            for (int mf = 0; mf < 4; ++mf)
                #pragma unroll
                for (int e = 0; e < 8; ++e)
                    rs[mf] += bf2f((unsigned short)af[mf][e]);
        }
        #pragma unroll
        for (int mf = 0; mf < 4; ++mf)
            #pragma unroll
            for (int nf = 0; nf < 4; ++nf)
                acc[mf][nf] = __builtin_amdgcn_mfma_f32_16x16x32_bf16(af[mf], bb[nf], acc[mf][nf], 0, 0, 0);
    }

    if (MODE == 0) {
        const int prow0 = mt * 128 + wr * 64;
        const int pcol0 = nt * 128 + wc * 64;
        #pragma unroll
        for (int mf = 0; mf < 4; ++mf)
            #pragma unroll
            for (int j = 0; j < 4; ++j) {
                const size_t rbase = (size_t)(prow0 + mf * 16 + g * 4 + j) * M_SZ + pcol0 + l15;
                #pragma unroll
                for (int nf = 0; nf < 4; ++nf)
                    Pout[rbase + nf * 16] = f2bf(__expf(acc[mf][nf][j]));
            }
    } else {
        const int orow0 = mt * 128 + wr * 64;
        const int ocol0 = nt * 128 + wc * 64;
        #pragma unroll
        for (int mf = 0; mf < 4; ++mf) {
            float d = rs[mf];
            d += __shfl_xor(d, 16);
            d += __shfl_xor(d, 32);
            #pragma unroll
            for (int j = 0; j < 4; ++j) {
                const float inv = 1.0f / __shfl(d, g * 4 + j);
                const size_t rbase = ((size_t)(orow0 + mf * 16 + g * 4 + j) * P_SZ + p) * C_SZ
                                   + ocol0 + l15;
                #pragma unroll
                for (int nf = 0; nf < 4; ++nf)
                    Oout[rbase + nf * 16] = acc[mf][nf][j] * inv;
            }
        }
    }
}

// ---------------- emergency fallback (no workspace): fp32, slow but correct ----------------
__global__ void emu_fallback(const float* __restrict__ inF, const float* __restrict__ wF,
                             float* __restrict__ out)
{
    __shared__ float sc[M_SZ];
    __shared__ float qs[C_SZ];
    __shared__ float wsum[4];
    const int b = blockIdx.x;
    const int tid = threadIdx.x;           // 256
    for (int c = tid; c < C_SZ; c += 256) qs[c] = inF[(size_t)b*C_SZ + c];
    __syncthreads();
    for (int p = 0; p < P_SZ; ++p) {
        const float* wp = wF + (size_t)p*M_SZ*C_SZ;
        for (int m = tid; m < M_SZ; m += 256) {
            float d = 0.f;
            const float* wr = wp + (size_t)m*C_SZ;
            for (int c = 0; c < C_SZ; ++c) d += qs[c]*wr[c];
            sc[m] = __expf(d);
        }
        __syncthreads();
        float part = 0.f;
        for (int m = tid; m < M_SZ; m += 256) part += sc[m];
        #pragma unroll
        for (int sft = 1; sft < 64; sft <<= 1) part += __shfl_xor(part, sft);
        if ((tid & 63) == 0) wsum[tid >> 6] = part;
        __syncthreads();
        const float rin = 1.0f / (wsum[0] + wsum[1] + wsum[2] + wsum[3]);
        float o0=0,o1=0,o2=0,o3=0;
        for (int m = 0; m < M_SZ; ++m) {
            const float pm = sc[m];
            const float4 w4 = *(const float4*)(wp + (size_t)m*C_SZ + tid*4);
            o0 += pm*w4.x; o1 += pm*w4.y; o2 += pm*w4.z; o3 += pm*w4.w;
        }
        float* op = out + ((size_t)b*P_SZ + p)*C_SZ + tid*4;
        op[0]=o0*rin; op[1]=o1*rin; op[2]=o2*rin; op[3]=o3*rin;
        __syncthreads();
    }
}

// ---------------- launcher ----------------
extern "C" void kernel_launch(void* const* d_in, const int* in_sizes, int n_in,
                              void* d_out, int out_size, void* d_ws, size_t ws_size,
                              hipStream_t stream)
{
    (void)in_sizes; (void)n_in; (void)out_size;
    const float* inF = (const float*)d_in[0];
    const float* wF  = (const float*)d_in[1];
    float* out = (float*)d_out;

    const size_t wbE  = (size_t)P_SZ * M_SZ * C_SZ;    // 16M
    const size_t qE   = (size_t)B_SZ * C_SZ;           // 8M
    const size_t pME  = (size_t)B_SZ * M_SZ;           // 16M (one p's P panel)
    const size_t pAll = pME * P_SZ;                    // 128M (all-p P)
    const size_t needBig   = (wbE*2 + qE + pAll) * sizeof(unsigned short);  // ~352 MB
    const size_t needMid   = (wbE*2 + qE + pME)  * sizeof(unsigned short);  // ~117 MB

    if (ws_size >= needBig) {
        unsigned short* wb = (unsigned short*)d_ws;
        unsigned short* wt = wb + wbE;
        unsigned short* qb = wt + wbE;
        unsigned short* Pb = qb + qE;
        cvt_q_kernel<<<(unsigned)(qE/4/256), 256, 0, stream>>>(inF, qb);
        cvt_w_kernel<<<P_SZ*64*32, 256, 0, stream>>>(wF, wb, wt);
        // GEMM1 all-p: S = Q * W_p^T -> exp -> P   (per p: M=8192, N=2048, K=1024)
        hipError_t e0 = hipFuncSetAttribute(reinterpret_cast<const void*>(&gemm8<C_SZ, 8, 0>),
                            hipFuncAttributeMaxDynamicSharedMemorySize, GLDS);
        (void)e0;
        gemm8<C_SZ, 8, 0><<<2048, 512, GLDS, stream>>>(
            qb, wb, Pb, nullptr, (size_t)0, (size_t)M_SZ * C_SZ);
        // GEMM2 all-p: O = P * W_p / denom        (per p: M=8192, N=1024, K=2048)
        hipError_t e1 = hipFuncSetAttribute(reinterpret_cast<const void*>(&gemm8<M_SZ, 4, 1>),
                            hipFuncAttributeMaxDynamicSharedMemorySize, GLDS);
        (void)e1;
        gemm8<M_SZ, 4, 1><<<1024, 512, GLDS, stream>>>(
            Pb, wt, nullptr, out, (size_t)B_SZ * M_SZ, (size_t)C_SZ * M_SZ);
    } else if (ws_size >= needMid) {
        unsigned short* wb = (unsigned short*)d_ws;
        unsigned short* wt = wb + wbE;
        unsigned short* qb = wt + wbE;
        unsigned short* Pb = qb + qE;
        cvt_q_kernel<<<(unsigned)(qE/4/256), 256, 0, stream>>>(inF, qb);
        cvt_w_kernel<<<P_SZ*64*32, 256, 0, stream>>>(wF, wb, wt);
        for (int p = 0; p < P_SZ; ++p) {
            gemm_tile<C_SZ, 16, 128, 0><<<1024, 256, 0, stream>>>(
                qb, wb + (size_t)p*M_SZ*C_SZ, Pb, nullptr, p);
            gemm_tile<M_SZ, 8, 64, 1><<<512, 256, 0, stream>>>(
                Pb, wt + (size_t)p*C_SZ*M_SZ, nullptr, out, p);
        }
    } else {
        emu_fallback<<<B_SZ, 256, 0, stream>>>(inF, wF, out);
    }
}